// Round 1
// baseline (1550.522 us; speedup 1.0000x reference)
//
#include <hip/hip_runtime.h>
#include <hip/hip_bf16.h>
#include <math.h>

#define NN 25000
#define EE 400000
#define BB 64
#define FF 32
#define EDD 8
#define HH 4
#define CC 32
#define HCC 128
#define LL 4
#define LINN 128

#define RSQRT_C 0.17677669529663687f  // 1/sqrt(32)

// ---------------- CSR build ----------------

__global__ void count_edges_kernel(const int* __restrict__ dst, int* __restrict__ deg) {
    int i = blockIdx.x * blockDim.x + threadIdx.x;
    if (i < EE) atomicAdd(&deg[dst[i]], 1);
}

__global__ void count_nodes_kernel(const int* __restrict__ bidx, float* __restrict__ counts) {
    int i = blockIdx.x * blockDim.x + threadIdx.x;
    if (i < NN) atomicAdd(&counts[bidx[i]], 1.0f);
}

// inclusive scan within 256-blocks; writes to rowp[i+1], block totals to blks
__global__ void scan1_kernel(const int* __restrict__ deg, int* __restrict__ rowp, int* __restrict__ blks) {
    __shared__ int s[256];
    int i = blockIdx.x * 256 + threadIdx.x;
    int v = (i < NN) ? deg[i] : 0;
    s[threadIdx.x] = v;
    __syncthreads();
    for (int off = 1; off < 256; off <<= 1) {
        int t = (threadIdx.x >= off) ? s[threadIdx.x - off] : 0;
        __syncthreads();
        s[threadIdx.x] += t;
        __syncthreads();
    }
    if (i < NN) rowp[i + 1] = s[threadIdx.x];
    if (threadIdx.x == 255) blks[blockIdx.x] = s[255];
}

__global__ void scan2_kernel(int* __restrict__ blks, int nb) {
    if (blockIdx.x == 0 && threadIdx.x == 0) {
        int acc = 0;
        for (int i = 0; i < nb; ++i) { int t = blks[i]; blks[i] = acc; acc += t; }
    }
}

__global__ void scan3_kernel(int* __restrict__ rowp, const int* __restrict__ blks) {
    int i = blockIdx.x * 256 + threadIdx.x;
    if (i < NN) rowp[i + 1] += blks[blockIdx.x];
    if (i == 0) rowp[0] = 0;
}

__global__ void copycur_kernel(const int* __restrict__ rowp, int* __restrict__ cur) {
    int i = blockIdx.x * 256 + threadIdx.x;
    if (i < NN) cur[i] = rowp[i];
}

__global__ void fill_kernel(const int* __restrict__ dst, int* __restrict__ cur, int* __restrict__ eid) {
    int i = blockIdx.x * blockDim.x + threadIdx.x;
    if (i < EE) {
        int pos = atomicAdd(&cur[dst[i]], 1);
        eid[pos] = i;
    }
}

// deterministic order: insertion-sort each node's edge list by edge id
__global__ void sortseg_kernel(const int* __restrict__ rowp, int* __restrict__ eid) {
    int n = blockIdx.x * 256 + threadIdx.x;
    if (n >= NN) return;
    int b = rowp[n], e = rowp[n + 1];
    for (int i = b + 1; i < e; ++i) {
        int key = eid[i];
        int j = i - 1;
        while (j >= b && eid[j] > key) { eid[j + 1] = eid[j]; --j; }
        eid[j + 1] = key;
    }
}

// ---------------- per-layer: q,k,v,skip projections ----------------
// 256 threads: c = tid&127, sel = tid>>7 (0: q,k ; 1: v,skip). Weights in regs.
__global__ __launch_bounds__(256) void qkvs_kernel(
    const float* __restrict__ hin,
    const float* __restrict__ Wq, const float* __restrict__ bq,
    const float* __restrict__ Wk, const float* __restrict__ bk,
    const float* __restrict__ Wv, const float* __restrict__ bv,
    const float* __restrict__ Ws, const float* __restrict__ bs,
    float* __restrict__ qo, float* __restrict__ ko,
    float* __restrict__ vo, float* __restrict__ so)
{
    __shared__ float xs[32][32];
    int c = threadIdx.x & 127;
    int sel = threadIdx.x >> 7;
    const float* WA = sel ? Wv : Wq;
    const float* WB = sel ? Ws : Wk;
    float wa[32], wb[32];
#pragma unroll
    for (int f = 0; f < 32; ++f) { wa[f] = WA[f * 128 + c]; wb[f] = WB[f * 128 + c]; }
    float ba = sel ? bv[c] : bq[c];
    float bb = sel ? bs[c] : bk[c];
    float* OA = sel ? vo : qo;
    float* OB = sel ? so : ko;

    for (int chunk = blockIdx.x * 32; chunk < NN; chunk += gridDim.x * 32) {
        __syncthreads();
        for (int i = threadIdx.x; i < 1024; i += 256) {
            int nn = chunk + (i >> 5);
            xs[i >> 5][i & 31] = (nn < NN) ? hin[nn * 32 + (i & 31)] : 0.0f;
        }
        __syncthreads();
        int nmax = NN - chunk; if (nmax > 32) nmax = 32;
        for (int nl = 0; nl < nmax; ++nl) {
            float accA = ba, accB = bb;
#pragma unroll
            for (int f = 0; f < 32; ++f) {
                float xv = xs[nl][f];
                accA += xv * wa[f];
                accB += xv * wb[f];
            }
            int node = chunk + nl;
            OA[node * 128 + c] = accA;
            OB[node * 128 + c] = accB;
        }
    }
}

// ---------------- fused attention + beta gate + Wlin + ELU + BN partials ----------------
// 4 waves/block, 1 dst node per wave. lane owns channels lane and lane+64.
__global__ __launch_bounds__(256) void attn_kernel(
    const float* __restrict__ qb, const float* __restrict__ kb,
    const float* __restrict__ vb, const float* __restrict__ skb,
    const float* __restrict__ eattr, const int* __restrict__ srcA,
    const int* __restrict__ rowp, const int* __restrict__ eid,
    const float* __restrict__ WeL, const float* __restrict__ beL,
    const float* __restrict__ WbL,
    const float* __restrict__ WlinL, const float* __restrict__ blinL,
    float* __restrict__ hlin, float* __restrict__ bnpart)
{
    __shared__ float sWe[8 * 128];
    __shared__ float sbe[128];
    __shared__ float sWb[384];
    __shared__ float sWlin[128 * 32];
    __shared__ float sblin[32];
    __shared__ float shc[4 * 128];
    __shared__ float sbn[64];

    int tid = threadIdx.x;
    for (int i = tid; i < 1024; i += 256) sWe[i] = WeL[i];
    if (tid < 128) sbe[tid] = beL[tid];
    for (int i = tid; i < 384; i += 256) sWb[i] = WbL[i];
    for (int i = tid; i < 4096; i += 256) sWlin[i] = WlinL[i];
    if (tid < 32) sblin[tid] = blinL[tid];
    if (tid < 64) sbn[tid] = 0.0f;
    __syncthreads();

    int w = tid >> 6;
    int lane = tid & 63;
    int n = blockIdx.x * 4 + w;

    if (n < NN) {
        float q0 = qb[n * 128 + lane];
        float q1 = qb[n * 128 + 64 + lane];
        float m0 = -1e30f, m1 = -1e30f;
        float s0 = 0.0f, s1 = 0.0f;
        float a0 = 0.0f, a1 = 0.0f;
        int beg = rowp[n], end = rowp[n + 1];
        for (int j = beg; j < end; ++j) {
            int e = eid[j];
            int sn = srcA[e];
            const float* ea = eattr + (long long)e * 8;
            float e0 = sbe[lane];
            float e1 = sbe[64 + lane];
#pragma unroll
            for (int d = 0; d < 8; ++d) {
                float av = ea[d];
                e0 += av * sWe[d * 128 + lane];
                e1 += av * sWe[d * 128 + 64 + lane];
            }
            float kj0 = kb[sn * 128 + lane] + e0;
            float kj1 = kb[sn * 128 + 64 + lane] + e1;
            float p0 = q0 * kj0;
            float p1 = q1 * kj1;
#pragma unroll
            for (int off = 1; off <= 16; off <<= 1) {
                p0 += __shfl_xor(p0, off);
                p1 += __shfl_xor(p1, off);
            }
            float al0 = p0 * RSQRT_C;
            float al1 = p1 * RSQRT_C;
            float vv0 = vb[sn * 128 + lane] + e0;
            float vv1 = vb[sn * 128 + 64 + lane] + e1;
            float mn0 = fmaxf(m0, al0), mn1 = fmaxf(m1, al1);
            float sc0 = __expf(m0 - mn0), sc1 = __expf(m1 - mn1);
            float w0 = __expf(al0 - mn0), w1 = __expf(al1 - mn1);
            s0 = s0 * sc0 + w0;  a0 = a0 * sc0 + w0 * vv0;  m0 = mn0;
            s1 = s1 * sc1 + w1;  a1 = a1 * sc1 + w1 * vv1;  m1 = mn1;
        }
        float out0 = (end > beg) ? (a0 / s0) : 0.0f;
        float out1 = (end > beg) ? (a1 / s1) : 0.0f;
        float sk0 = skb[n * 128 + lane];
        float sk1 = skb[n * 128 + 64 + lane];
        // beta = sigmoid([out, skip, out-skip] . Wbeta)
        float t = out0 * sWb[lane] + sk0 * sWb[128 + lane] + (out0 - sk0) * sWb[256 + lane]
                + out1 * sWb[64 + lane] + sk1 * sWb[192 + lane] + (out1 - sk1) * sWb[320 + lane];
#pragma unroll
        for (int off = 1; off <= 32; off <<= 1) t += __shfl_xor(t, off);
        float beta = 1.0f / (1.0f + __expf(-t));
        float hc0 = beta * sk0 + (1.0f - beta) * out0;
        float hc1 = beta * sk1 + (1.0f - beta) * out1;
        shc[w * 128 + lane] = hc0;
        shc[w * 128 + 64 + lane] = hc1;
        // Wlin: 128 -> 32, split across lane halves
        int cc = lane & 31;
        int half = lane >> 5;
        float acc = 0.0f;
#pragma unroll 8
        for (int i = 0; i < 64; ++i) {
            int ch = half * 64 + i;
            acc += shc[w * 128 + ch] * sWlin[ch * 32 + cc];
        }
        acc += __shfl_xor(acc, 32);
        if (lane < 32) {
            float hv = acc + sblin[lane];
            hv = (hv > 0.0f) ? hv : (expm1f(hv));
            hlin[n * 32 + lane] = hv;
            atomicAdd(&sbn[lane], hv);
            atomicAdd(&sbn[32 + lane], hv * hv);
        }
    }
    __syncthreads();
    if (tid < 64) atomicAdd(&bnpart[tid], sbn[tid]);
}

// ---------------- BN finalize ----------------
__global__ void bn_fin_kernel(const float* __restrict__ bnpart,
                              const float* __restrict__ gamma, const float* __restrict__ beta,
                              float* __restrict__ ss) {
    int c = threadIdx.x;
    if (c < 32) {
        float mean = bnpart[c] * (1.0f / NN);
        float var = bnpart[32 + c] * (1.0f / NN) - mean * mean;
        float scale = gamma[c] * rsqrtf(var + 1e-5f);
        ss[c] = scale;
        ss[32 + c] = beta[c] - mean * scale;
    }
}

// ---------------- normalize + pooling atomics ----------------
__device__ __forceinline__ unsigned fmap_u(float x) {
    unsigned u = __float_as_uint(x);
    return (u & 0x80000000u) ? ~u : (u | 0x80000000u);
}
__device__ __forceinline__ float funmap_u(unsigned u) {
    unsigned b = (u & 0x80000000u) ? (u & 0x7fffffffu) : ~u;
    return __uint_as_float(b);
}

__global__ void norm_pool_kernel(const float* __restrict__ hl, const float* __restrict__ ss,
                                 const int* __restrict__ bidx, float* __restrict__ hc,
                                 unsigned* __restrict__ gmax, float* __restrict__ gsum, int doPool) {
    int i = blockIdx.x * blockDim.x + threadIdx.x;
    const int tot = NN * 32;
    for (; i < tot; i += gridDim.x * blockDim.x) {
        int c = i & 31;
        int n = i >> 5;
        float val = hl[i] * ss[c] + ss[32 + c];
        hc[i] = val;
        if (doPool) {
            int b = bidx[n];
            atomicMax(&gmax[b * 32 + c], fmap_u(val));
            atomicAdd(&gsum[b * 32 + c], val);
        }
    }
}

__global__ void pool_accum_kernel(const unsigned* __restrict__ gmax, const float* __restrict__ gsum,
                                  const float* __restrict__ counts, float* __restrict__ rep) {
    int i = blockIdx.x * blockDim.x + threadIdx.x;
    if (i < BB * 32) {
        int b = i >> 5, c = i & 31;
        rep[b * 64 + c] += funmap_u(gmax[i]);
        rep[b * 64 + 32 + c] += gsum[i] / counts[b];
    }
}

// ---------------- readout MLP ----------------
__device__ __forceinline__ float eluf(float x) { return x > 0.0f ? x : expm1f(x); }

__global__ __launch_bounds__(128) void readout_kernel(
    const float* __restrict__ rep,
    const float* __restrict__ W1, const float* __restrict__ b1,
    const float* __restrict__ W2, const float* __restrict__ b2,
    const float* __restrict__ W3, const float* __restrict__ b3,
    float* __restrict__ out)
{
    __shared__ float z1[64 * 128];
    __shared__ float z2[64 * 64];
    int t = threadIdx.x;
    for (int idx = t; idx < 64 * 128; idx += 128) {
        int g = idx >> 7, j = idx & 127;
        float acc = b1[j];
        for (int i = 0; i < 64; ++i) acc += rep[g * 64 + i] * W1[i * 128 + j];
        z1[idx] = eluf(acc);
    }
    __syncthreads();
    for (int idx = t; idx < 64 * 64; idx += 128) {
        int g = idx >> 6, j = idx & 63;
        float acc = b2[j];
        for (int i = 0; i < 128; ++i) acc += z1[g * 128 + i] * W2[i * 64 + j];
        z2[idx] = eluf(acc);
    }
    __syncthreads();
    if (t < 64) {
        float acc = b3[0];
        for (int i = 0; i < 64; ++i) acc += z2[t * 64 + i] * W3[i];
        out[t] = acc;
    }
}

// ---------------- host ----------------

extern "C" void kernel_launch(void* const* d_in, const int* in_sizes, int n_in,
                              void* d_out, int out_size, void* d_ws, size_t ws_size,
                              hipStream_t stream) {
    const float* x      = (const float*)d_in[0];
    const float* eattr  = (const float*)d_in[1];
    const int*   eidx   = (const int*)d_in[2];
    const int*   bidx   = (const int*)d_in[3];
    const float* Wq     = (const float*)d_in[4];
    const float* bq     = (const float*)d_in[5];
    const float* Wk     = (const float*)d_in[6];
    const float* bk     = (const float*)d_in[7];
    const float* Wv     = (const float*)d_in[8];
    const float* bv     = (const float*)d_in[9];
    const float* We     = (const float*)d_in[10];
    const float* be     = (const float*)d_in[11];
    const float* Wskip  = (const float*)d_in[12];
    const float* bskip  = (const float*)d_in[13];
    const float* Wbeta  = (const float*)d_in[14];
    const float* Wlin   = (const float*)d_in[15];
    const float* blin   = (const float*)d_in[16];
    const float* bng    = (const float*)d_in[17];
    const float* bnb    = (const float*)d_in[18];
    const float* W1     = (const float*)d_in[19];
    const float* b1     = (const float*)d_in[20];
    const float* W2     = (const float*)d_in[21];
    const float* b2     = (const float*)d_in[22];
    const float* W3     = (const float*)d_in[23];
    const float* b3     = (const float*)d_in[24];
    float* out = (float*)d_out;

    char* ws = (char*)d_ws;
    size_t off = 0;
    auto alloc = [&](size_t bytes) -> char* {
        char* p = ws + off;
        off = (off + bytes + 255) & ~(size_t)255;
        return p;
    };
    int*      rowp   = (int*)alloc((NN + 1) * 4);
    int*      deg    = (int*)alloc(NN * 4);
    int*      cur    = (int*)alloc(NN * 4);
    int*      csre   = (int*)alloc(EE * 4);
    int*      blks   = (int*)alloc(128 * 4);
    float*    counts = (float*)alloc(BB * 4);
    float*    qB     = (float*)alloc((size_t)NN * 128 * 4);
    float*    kB     = (float*)alloc((size_t)NN * 128 * 4);
    float*    vB     = (float*)alloc((size_t)NN * 128 * 4);
    float*    skB    = (float*)alloc((size_t)NN * 128 * 4);
    float*    hlin   = (float*)alloc((size_t)NN * 32 * 4);
    float*    hcur   = (float*)alloc((size_t)NN * 32 * 4);
    float*    bnpart = (float*)alloc(64 * 4);
    float*    bnss   = (float*)alloc(64 * 4);
    unsigned* gmax   = (unsigned*)alloc(BB * 32 * 4);
    float*    gsum   = (float*)alloc(BB * 32 * 4);
    float*    rep    = (float*)alloc(BB * 64 * 4);

    const int* srcA = eidx;
    const int* dstA = eidx + EE;

    // --- graph prep (once per call) ---
    hipMemsetAsync(deg, 0, NN * 4, stream);
    hipMemsetAsync(counts, 0, BB * 4, stream);
    hipMemsetAsync(rep, 0, BB * 64 * 4, stream);

    count_edges_kernel<<<(EE + 255) / 256, 256, 0, stream>>>(dstA, deg);
    count_nodes_kernel<<<(NN + 255) / 256, 256, 0, stream>>>(bidx, counts);
    scan1_kernel<<<98, 256, 0, stream>>>(deg, rowp, blks);
    scan2_kernel<<<1, 1, 0, stream>>>(blks, 98);
    scan3_kernel<<<98, 256, 0, stream>>>(rowp, blks);
    copycur_kernel<<<98, 256, 0, stream>>>(rowp, cur);
    fill_kernel<<<(EE + 255) / 256, 256, 0, stream>>>(dstA, cur, csre);
    sortseg_kernel<<<98, 256, 0, stream>>>(rowp, csre);

    const float* hin = x;
    for (int l = 0; l < LL; ++l) {
        qkvs_kernel<<<782, 256, 0, stream>>>(
            hin,
            Wq + l * FF * HCC, bq + l * HCC,
            Wk + l * FF * HCC, bk + l * HCC,
            Wv + l * FF * HCC, bv + l * HCC,
            Wskip + l * FF * HCC, bskip + l * HCC,
            qB, kB, vB, skB);

        hipMemsetAsync(bnpart, 0, 64 * 4, stream);
        if (l > 0) {
            hipMemsetAsync(gmax, 0, BB * 32 * 4, stream);
            hipMemsetAsync(gsum, 0, BB * 32 * 4, stream);
        }

        attn_kernel<<<(NN + 3) / 4, 256, 0, stream>>>(
            qB, kB, vB, skB, eattr, srcA, rowp, csre,
            We + l * EDD * HCC, be + l * HCC,
            Wbeta + l * 3 * HCC,
            Wlin + l * HCC * FF, blin + l * FF,
            hlin, bnpart);

        bn_fin_kernel<<<1, 32, 0, stream>>>(bnpart, bng + l * FF, bnb + l * FF, bnss);

        norm_pool_kernel<<<3125, 256, 0, stream>>>(hlin, bnss, bidx, hcur, gmax, gsum, (l > 0) ? 1 : 0);

        if (l > 0) {
            pool_accum_kernel<<<8, 256, 0, stream>>>(gmax, gsum, counts, rep);
        }
        hin = hcur;
    }

    readout_kernel<<<1, 128, 0, stream>>>(rep, W1, b1, W2, b2, W3, b3, out);
}

// Round 3
// 961.706 us; speedup vs baseline: 1.6123x; 1.6123x over previous
//
#include <hip/hip_runtime.h>
#include <hip/hip_bf16.h>
#include <math.h>

#define NN 25000
#define EE 400000
#define BB 64
#define FF 32
#define EDD 8
#define HH 4
#define CC 32
#define HCC 128
#define LL 4
#define LINN 128

#define RSQRT_C 0.17677669529663687f  // 1/sqrt(32)
#define NREP 16                        // bnpart replicas

// ---------------- CSR build ----------------

__global__ void count_kernel(const int* __restrict__ dst, int* __restrict__ deg,
                             const int* __restrict__ bidx, float* __restrict__ counts) {
    int i = blockIdx.x * blockDim.x + threadIdx.x;
    if (i < EE) atomicAdd(&deg[dst[i]], 1);
    if (i < NN) atomicAdd(&counts[bidx[i]], 1.0f);
}

// inclusive scan within 256-blocks; writes to rowp[i+1], block totals to blks
__global__ void scan1_kernel(const int* __restrict__ deg, int* __restrict__ rowp, int* __restrict__ blks) {
    __shared__ int s[256];
    int i = blockIdx.x * 256 + threadIdx.x;
    int v = (i < NN) ? deg[i] : 0;
    s[threadIdx.x] = v;
    __syncthreads();
    for (int off = 1; off < 256; off <<= 1) {
        int t = (threadIdx.x >= off) ? s[threadIdx.x - off] : 0;
        __syncthreads();
        s[threadIdx.x] += t;
        __syncthreads();
    }
    if (i < NN) rowp[i + 1] = s[threadIdx.x];
    if (threadIdx.x == 255) blks[blockIdx.x] = s[255];
}

// parallel exclusive scan of block totals (nb <= 128)
__global__ void scan2_kernel(int* __restrict__ blks, int nb) {
    __shared__ int s[128];
    int t = threadIdx.x;
    int v = (t < nb) ? blks[t] : 0;
    s[t] = v;
    __syncthreads();
    for (int off = 1; off < 128; off <<= 1) {
        int u = (t >= off) ? s[t - off] : 0;
        __syncthreads();
        s[t] += u;
        __syncthreads();
    }
    if (t < nb) blks[t] = s[t] - v;  // exclusive
}

__global__ void scan3_kernel(int* __restrict__ rowp, const int* __restrict__ blks) {
    int i = blockIdx.x * 256 + threadIdx.x;
    if (i < NN) rowp[i + 1] += blks[blockIdx.x];
    if (i == 0) rowp[0] = 0;
}

__global__ void copycur_kernel(const int* __restrict__ rowp, int* __restrict__ cur) {
    int i = blockIdx.x * 256 + threadIdx.x;
    if (i < NN) cur[i] = rowp[i];
}

__global__ void fill_kernel(const int* __restrict__ dst, int* __restrict__ cur, int* __restrict__ eid) {
    int i = blockIdx.x * blockDim.x + threadIdx.x;
    if (i < EE) {
        int pos = atomicAdd(&cur[dst[i]], 1);
        eid[pos] = i;
    }
}

// deterministic order: insertion-sort each node's edge list by edge id
__global__ void sortseg_kernel(const int* __restrict__ rowp, int* __restrict__ eid) {
    int n = blockIdx.x * 256 + threadIdx.x;
    if (n >= NN) return;
    int b = rowp[n], e = rowp[n + 1];
    for (int i = b + 1; i < e; ++i) {
        int key = eid[i];
        int j = i - 1;
        while (j >= b && eid[j] > key) { eid[j + 1] = eid[j]; --j; }
        eid[j + 1] = key;
    }
}

// gather src + edge-attr into CSR order (once per call, reused 4 layers)
__global__ void csr_gather_kernel(const int* __restrict__ csre, const int* __restrict__ srcA,
                                  const float* __restrict__ eattr,
                                  int* __restrict__ csrsrc, float4* __restrict__ ecsr) {
    int j = blockIdx.x * blockDim.x + threadIdx.x;
    if (j < EE) {
        int e = csre[j];
        csrsrc[j] = srcA[e];
        const float4* s = (const float4*)(eattr + (size_t)e * 8);
        ecsr[(size_t)j * 2] = s[0];
        ecsr[(size_t)j * 2 + 1] = s[1];
    }
}

// ---------------- per-layer: q,k,v,skip projections ----------------
// wave 0: q, wave 1: k, wave 2: v, wave 3: skip. lane owns channels 2l, 2l+1.
// outputs: qB float2/lane, kvB float4/lane {k0,k1,v0,v1} (written as float2 halves), skB float2/lane.
__global__ __launch_bounds__(256) void qkvs_kernel(
    const float* __restrict__ hin,
    const float* __restrict__ Wq, const float* __restrict__ bq,
    const float* __restrict__ Wk, const float* __restrict__ bk,
    const float* __restrict__ Wv, const float* __restrict__ bv,
    const float* __restrict__ Ws, const float* __restrict__ bs,
    float2* __restrict__ qo, float2* __restrict__ kvo,
    float2* __restrict__ so)
{
    __shared__ float xs[32][32];
    int lane = threadIdx.x & 63;
    int sel = threadIdx.x >> 6;
    const float* W = (sel == 0) ? Wq : (sel == 1) ? Wk : (sel == 2) ? Wv : Ws;
    const float* bias = (sel == 0) ? bq : (sel == 1) ? bk : (sel == 2) ? bv : bs;
    float w0[32], w1[32];
#pragma unroll
    for (int f = 0; f < 32; ++f) {
        float2 t = *(const float2*)&W[f * 128 + 2 * lane];
        w0[f] = t.x; w1[f] = t.y;
    }
    float2 bvv = *(const float2*)&bias[2 * lane];

    for (int chunk = blockIdx.x * 32; chunk < NN; chunk += gridDim.x * 32) {
        __syncthreads();
        for (int i = threadIdx.x; i < 1024; i += 256) {
            int nn = chunk + (i >> 5);
            xs[i >> 5][i & 31] = (nn < NN) ? hin[nn * 32 + (i & 31)] : 0.0f;
        }
        __syncthreads();
        int nmax = NN - chunk; if (nmax > 32) nmax = 32;
        for (int nl = 0; nl < nmax; ++nl) {
            float a0 = bvv.x, a1 = bvv.y;
#pragma unroll
            for (int f = 0; f < 32; ++f) {
                float xv = xs[nl][f];
                a0 += xv * w0[f];
                a1 += xv * w1[f];
            }
            size_t node = (size_t)(chunk + nl);
            if (sel == 0)      qo[node * 64 + lane] = make_float2(a0, a1);
            else if (sel == 1) kvo[node * 128 + 2 * lane]     = make_float2(a0, a1);
            else if (sel == 2) kvo[node * 128 + 2 * lane + 1] = make_float2(a0, a1);
            else               so[node * 64 + lane] = make_float2(a0, a1);
        }
    }
}

// ---------------- fused attention + beta gate + Wlin + ELU + BN partials ----------------
// 4 waves/block, 1 dst node per wave. lane owns channels 2*lane, 2*lane+1 (same head).
template <int ORDERED>
__global__ __launch_bounds__(256) void attn_kernel(
    const float2* __restrict__ qb, const float4* __restrict__ kvb,
    const float2* __restrict__ skb,
    const float4* __restrict__ eb4,       // ORDERED: ecsr (2 float4/slot), else eattr
    const int* __restrict__ srcArr,       // ORDERED: csrsrc[j], else srcA[e]
    const int* __restrict__ emap,         // csre (used only when !ORDERED)
    const int* __restrict__ rowp,
    const float* __restrict__ WeL, const float* __restrict__ beL,
    const float* __restrict__ WbL,
    const float* __restrict__ WlinL, const float* __restrict__ blinL,
    float* __restrict__ hlin, float* __restrict__ bnpart)
{
    __shared__ float shc[4 * 128];
    __shared__ float sbn[64];

    int tid = threadIdx.x;
    if (tid < 64) sbn[tid] = 0.0f;
    __syncthreads();

    int w = tid >> 6;
    int lane = tid & 63;
    int n = blockIdx.x * 4 + w;

    if (n < NN) {
        // per-lane weights in registers
        float w0[8], w1[8];
#pragma unroll
        for (int d = 0; d < 8; ++d) {
            float2 t = *(const float2*)&WeL[d * 128 + 2 * lane];
            w0[d] = t.x; w1[d] = t.y;
        }
        float2 be2 = *(const float2*)&beL[2 * lane];
        float2 wbo = *(const float2*)&WbL[2 * lane];
        float2 wbs = *(const float2*)&WbL[128 + 2 * lane];
        float2 wbd = *(const float2*)&WbL[256 + 2 * lane];

        float2 q2 = qb[(size_t)n * 64 + lane];
        float2 sk = skb[(size_t)n * 64 + lane];

        int beg = rowp[n], end = rowp[n + 1];
        int cnt = end - beg;

        float m = -1e30f, s = 0.0f, a0 = 0.0f, a1 = 0.0f;

        float4 kvA = make_float4(0.f, 0.f, 0.f, 0.f);
        float4 eaA0 = kvA, eaA1 = kvA;
        int eB = 0, snB = 0;

        if (cnt > 0) {
            int eA = ORDERED ? beg : emap[beg];
            int snA = srcArr[ORDERED ? beg : eA];
            kvA  = kvb[(size_t)snA * 64 + lane];
            eaA0 = eb4[(size_t)eA * 2];
            eaA1 = eb4[(size_t)eA * 2 + 1];
            if (cnt > 1) {
                eB  = ORDERED ? (beg + 1) : emap[beg + 1];
                snB = srcArr[ORDERED ? (beg + 1) : eB];
            }
        }

        for (int j = beg; j < end; ++j) {
            float4 kvN = kvA, eaN0 = eaA0, eaN1 = eaA1;
            int eC = eB, snC = snB;
            if (j + 1 < end) {
                kvN  = kvb[(size_t)snB * 64 + lane];
                eaN0 = eb4[(size_t)eB * 2];
                eaN1 = eb4[(size_t)eB * 2 + 1];
            }
            if (j + 2 < end) {
                eC  = ORDERED ? (j + 2) : emap[j + 2];
                snC = srcArr[ORDERED ? (j + 2) : eC];
            }
            // compute with current edge (A)
            float e0 = be2.x, e1 = be2.y;
            e0 += eaA0.x * w0[0] + eaA0.y * w0[1] + eaA0.z * w0[2] + eaA0.w * w0[3]
                + eaA1.x * w0[4] + eaA1.y * w0[5] + eaA1.z * w0[6] + eaA1.w * w0[7];
            e1 += eaA0.x * w1[0] + eaA0.y * w1[1] + eaA0.z * w1[2] + eaA0.w * w1[3]
                + eaA1.x * w1[4] + eaA1.y * w1[5] + eaA1.z * w1[6] + eaA1.w * w1[7];
            float kj0 = kvA.x + e0;
            float kj1 = kvA.y + e1;
            float p = q2.x * kj0 + q2.y * kj1;
#pragma unroll
            for (int off = 1; off <= 8; off <<= 1) p += __shfl_xor(p, off);
            float al = p * RSQRT_C;
            float vv0 = kvA.z + e0;
            float vv1 = kvA.w + e1;
            float mn = fmaxf(m, al);
            float sc = __expf(m - mn);
            float wg = __expf(al - mn);
            s  = s * sc + wg;
            a0 = a0 * sc + wg * vv0;
            a1 = a1 * sc + wg * vv1;
            m = mn;
            // rotate pipeline
            kvA = kvN; eaA0 = eaN0; eaA1 = eaN1; snB = snC; eB = eC;
        }

        float out0 = (cnt > 0) ? (a0 / s) : 0.0f;
        float out1 = (cnt > 0) ? (a1 / s) : 0.0f;

        float t = out0 * wbo.x + sk.x * wbs.x + (out0 - sk.x) * wbd.x
                + out1 * wbo.y + sk.y * wbs.y + (out1 - sk.y) * wbd.y;
#pragma unroll
        for (int off = 1; off <= 32; off <<= 1) t += __shfl_xor(t, off);
        float beta = 1.0f / (1.0f + __expf(-t));
        float hc0 = beta * sk.x + (1.0f - beta) * out0;
        float hc1 = beta * sk.y + (1.0f - beta) * out1;
        shc[w * 128 + 2 * lane]     = hc0;
        shc[w * 128 + 2 * lane + 1] = hc1;
        // same-wave LDS RAW: no barrier needed
        int cc = lane & 31;
        int half = lane >> 5;
        float acc = 0.0f;
#pragma unroll 8
        for (int i = 0; i < 64; ++i) {
            int ch = half * 64 + i;
            acc += shc[w * 128 + ch] * WlinL[ch * 32 + cc];
        }
        acc += __shfl_xor(acc, 32);
        if (lane < 32) {
            float hv = acc + blinL[lane];
            hv = (hv > 0.0f) ? hv : expm1f(hv);
            hlin[n * 32 + lane] = hv;
            atomicAdd(&sbn[lane], hv);
            atomicAdd(&sbn[32 + lane], hv * hv);
        }
    }
    __syncthreads();
    if (tid < 64) atomicAdd(&bnpart[(blockIdx.x & (NREP - 1)) * 64 + tid], sbn[tid]);
}

// ---------------- normalize (BN finalize inline) + pooling atomics ----------------
__device__ __forceinline__ unsigned fmap_u(float x) {
    unsigned u = __float_as_uint(x);
    return (u & 0x80000000u) ? ~u : (u | 0x80000000u);
}
__device__ __forceinline__ float funmap_u(unsigned u) {
    unsigned b = (u & 0x80000000u) ? (u & 0x7fffffffu) : ~u;
    return __uint_as_float(b);
}

__global__ void norm_pool_kernel(const float* __restrict__ hl, const float* __restrict__ bnpart,
                                 const float* __restrict__ gamma, const float* __restrict__ bnbeta,
                                 const int* __restrict__ bidx, float* __restrict__ hc,
                                 unsigned* __restrict__ gmax, float* __restrict__ gsum, int doPool) {
    int i0 = blockIdx.x * blockDim.x + threadIdx.x;
    int stride = gridDim.x * blockDim.x;   // multiple of 32 -> c fixed per thread
    int c = i0 & 31;
    float sm = 0.0f, sq = 0.0f;
#pragma unroll
    for (int r = 0; r < NREP; ++r) { sm += bnpart[r * 64 + c]; sq += bnpart[r * 64 + 32 + c]; }
    float mean = sm * (1.0f / NN);
    float var = sq * (1.0f / NN) - mean * mean;
    float scale = gamma[c] * rsqrtf(var + 1e-5f);
    float shift = bnbeta[c] - mean * scale;
    const int tot = NN * 32;
    for (int i = i0; i < tot; i += stride) {
        int n = i >> 5;
        float val = hl[i] * scale + shift;
        hc[i] = val;
        if (doPool) {
            int b = bidx[n];
            atomicMax(&gmax[b * 32 + c], fmap_u(val));
            atomicAdd(&gsum[b * 32 + c], val);
        }
    }
}

__global__ void pool_accum_kernel(const unsigned* __restrict__ gmax, const float* __restrict__ gsum,
                                  const float* __restrict__ counts, float* __restrict__ rep) {
    int i = blockIdx.x * blockDim.x + threadIdx.x;
    if (i < BB * 32) {
        int b = i >> 5, c = i & 31;
        rep[b * 64 + c] += funmap_u(gmax[i]);
        rep[b * 64 + 32 + c] += gsum[i] / counts[b];
    }
}

// ---------------- readout MLP: one block per graph ----------------
__device__ __forceinline__ float eluf(float x) { return x > 0.0f ? x : expm1f(x); }

__global__ __launch_bounds__(128) void readout_kernel(
    const float* __restrict__ rep,
    const float* __restrict__ W1, const float* __restrict__ b1,
    const float* __restrict__ W2, const float* __restrict__ b2,
    const float* __restrict__ W3, const float* __restrict__ b3,
    float* __restrict__ out)
{
    __shared__ float sr[64];
    __shared__ float sz1[128];
    __shared__ float sz2[64];
    int g = blockIdx.x;
    int t = threadIdx.x;
    if (t < 64) sr[t] = rep[g * 64 + t];
    __syncthreads();
    float acc = b1[t];
#pragma unroll 8
    for (int i = 0; i < 64; ++i) acc += sr[i] * W1[i * 128 + t];
    sz1[t] = eluf(acc);
    __syncthreads();
    if (t < 64) {
        float a2 = b2[t];
#pragma unroll 8
        for (int i = 0; i < 128; ++i) a2 += sz1[i] * W2[i * 64 + t];
        sz2[t] = eluf(a2);
    }
    __syncthreads();
    if (t < 64) {
        float p = sz2[t] * W3[t];
#pragma unroll
        for (int off = 1; off <= 32; off <<= 1) p += __shfl_xor(p, off);
        if (t == 0) out[g] = p + b3[0];
    }
}

// ---------------- host ----------------

extern "C" void kernel_launch(void* const* d_in, const int* in_sizes, int n_in,
                              void* d_out, int out_size, void* d_ws, size_t ws_size,
                              hipStream_t stream) {
    const float* x      = (const float*)d_in[0];
    const float* eattr  = (const float*)d_in[1];
    const int*   eidx   = (const int*)d_in[2];
    const int*   bidx   = (const int*)d_in[3];
    const float* Wq     = (const float*)d_in[4];
    const float* bq     = (const float*)d_in[5];
    const float* Wk     = (const float*)d_in[6];
    const float* bk     = (const float*)d_in[7];
    const float* Wv     = (const float*)d_in[8];
    const float* bv     = (const float*)d_in[9];
    const float* We     = (const float*)d_in[10];
    const float* be     = (const float*)d_in[11];
    const float* Wskip  = (const float*)d_in[12];
    const float* bskip  = (const float*)d_in[13];
    const float* Wbeta  = (const float*)d_in[14];
    const float* Wlin   = (const float*)d_in[15];
    const float* blin   = (const float*)d_in[16];
    const float* bng    = (const float*)d_in[17];
    const float* bnb    = (const float*)d_in[18];
    const float* W1     = (const float*)d_in[19];
    const float* b1     = (const float*)d_in[20];
    const float* W2     = (const float*)d_in[21];
    const float* b2     = (const float*)d_in[22];
    const float* W3     = (const float*)d_in[23];
    const float* b3     = (const float*)d_in[24];
    float* out = (float*)d_out;

    char* ws = (char*)d_ws;
    size_t off = 0;
    auto alloc = [&](size_t bytes) -> char* {
        char* p = ws + off;
        off = (off + bytes + 255) & ~(size_t)255;
        return p;
    };
    int*    rowp   = (int*)alloc((NN + 1) * 4);
    int*    deg    = (int*)alloc(NN * 4);
    int*    cur    = (int*)alloc(NN * 4);
    int*    csre   = (int*)alloc(EE * 4);
    int*    blks   = (int*)alloc(128 * 4);
    float*  counts = (float*)alloc(BB * 4 + BB * 64 * 4);   // counts + rep contiguous
    float*  rep    = counts + BB;
    float2* qB     = (float2*)alloc((size_t)NN * 64 * 8);
    float4* kvB    = (float4*)alloc((size_t)NN * 64 * 16);
    float2* skB    = (float2*)alloc((size_t)NN * 64 * 8);
    float*  hlin   = (float*)alloc((size_t)NN * 32 * 4);
    float*  hcur   = (float*)alloc((size_t)NN * 32 * 4);
    char*   lstats = alloc(NREP * 64 * 4 + BB * 32 * 4 * 2); // bnpart + gmax + gsum
    float*    bnpart = (float*)lstats;
    unsigned* gmax   = (unsigned*)(lstats + NREP * 64 * 4);
    float*    gsum   = (float*)(lstats + NREP * 64 * 4 + BB * 32 * 4);
    const size_t lstats_bytes = NREP * 64 * 4 + BB * 32 * 4 * 2;

    // optional CSR-ordered copies (use only if workspace allows)
    int*    csrsrc = (int*)alloc(EE * 4);
    float4* ecsr   = (float4*)alloc((size_t)EE * 32);
    const int ordered = (off <= ws_size) ? 1 : 0;

    const int* srcA = eidx;
    const int* dstA = eidx + EE;

    // --- graph prep (once per call) ---
    (void)hipMemsetAsync(deg, 0, NN * 4, stream);
    (void)hipMemsetAsync(counts, 0, BB * 4 + BB * 64 * 4, stream);

    count_kernel<<<(EE + 255) / 256, 256, 0, stream>>>(dstA, deg, bidx, counts);
    scan1_kernel<<<98, 256, 0, stream>>>(deg, rowp, blks);
    scan2_kernel<<<1, 128, 0, stream>>>(blks, 98);
    scan3_kernel<<<98, 256, 0, stream>>>(rowp, blks);
    copycur_kernel<<<98, 256, 0, stream>>>(rowp, cur);
    fill_kernel<<<(EE + 255) / 256, 256, 0, stream>>>(dstA, cur, csre);
    sortseg_kernel<<<98, 256, 0, stream>>>(rowp, csre);
    if (ordered) {
        csr_gather_kernel<<<(EE + 255) / 256, 256, 0, stream>>>(csre, srcA, eattr, csrsrc, ecsr);
    }

    const float* hin = x;
    for (int l = 0; l < LL; ++l) {
        qkvs_kernel<<<782, 256, 0, stream>>>(
            hin,
            Wq + l * FF * HCC, bq + l * HCC,
            Wk + l * FF * HCC, bk + l * HCC,
            Wv + l * FF * HCC, bv + l * HCC,
            Wskip + l * FF * HCC, bskip + l * HCC,
            qB, (float2*)kvB, skB);

        (void)hipMemsetAsync(lstats, 0, lstats_bytes, stream);

        if (ordered) {
            attn_kernel<1><<<(NN + 3) / 4, 256, 0, stream>>>(
                qB, kvB, skB, ecsr, csrsrc, csre, rowp,
                We + l * EDD * HCC, be + l * HCC,
                Wbeta + l * 3 * HCC,
                Wlin + l * HCC * FF, blin + l * FF,
                hlin, bnpart);
        } else {
            attn_kernel<0><<<(NN + 3) / 4, 256, 0, stream>>>(
                qB, kvB, skB, (const float4*)eattr, srcA, csre, rowp,
                We + l * EDD * HCC, be + l * HCC,
                Wbeta + l * 3 * HCC,
                Wlin + l * HCC * FF, blin + l * FF,
                hlin, bnpart);
        }

        norm_pool_kernel<<<800, 256, 0, stream>>>(hlin, bnpart, bng + l * FF, bnb + l * FF,
                                                  bidx, hcur, gmax, gsum, (l > 0) ? 1 : 0);

        if (l > 0) {
            pool_accum_kernel<<<8, 256, 0, stream>>>(gmax, gsum, counts, rep);
        }
        hin = hcur;
    }

    readout_kernel<<<64, 128, 0, stream>>>(rep, W1, b1, W2, b2, W3, b3, out);
}

// Round 4
// 809.980 us; speedup vs baseline: 1.9143x; 1.1873x over previous
//
#include <hip/hip_runtime.h>
#include <hip/hip_bf16.h>
#include <hip/hip_fp16.h>
#include <math.h>

#define NN 25000
#define EE 400000
#define BB 64
#define FF 32
#define EDD 8
#define HH 4
#define CC 32
#define HCC 128
#define LL 4
#define LINN 128

#define RSQRT_C 0.17677669529663687f  // 1/sqrt(32)
#define NREP 16                        // bnpart replicas
#define LSTATS_WORDS (NREP * 64 + BB * 32 * 2)   // bnpart + gmax + gsum

// ---------------- CSR build ----------------

__global__ void deg_kernel(const int* __restrict__ dst, int* __restrict__ deg) {
    int i = blockIdx.x * blockDim.x + threadIdx.x;
    if (i < EE) atomicAdd(&deg[dst[i]], 1);
}

// batch_index is sorted: counts via binary search, zero atomics
__global__ void counts_kernel(const int* __restrict__ bidx, float* __restrict__ counts) {
    int b = threadIdx.x;
    if (b < BB) {
        int lo = 0, hi = NN;
        while (lo < hi) { int mid = (lo + hi) >> 1; if (bidx[mid] < b) lo = mid + 1; else hi = mid; }
        int s = lo;
        lo = 0; hi = NN;
        while (lo < hi) { int mid = (lo + hi) >> 1; if (bidx[mid] < b + 1) lo = mid + 1; else hi = mid; }
        counts[b] = (float)(lo - s);
    }
}

// inclusive scan within 256-blocks; writes to rowp[i+1], block totals to blks
__global__ void scan1_kernel(const int* __restrict__ deg, int* __restrict__ rowp, int* __restrict__ blks) {
    __shared__ int s[256];
    int i = blockIdx.x * 256 + threadIdx.x;
    int v = (i < NN) ? deg[i] : 0;
    s[threadIdx.x] = v;
    __syncthreads();
    for (int off = 1; off < 256; off <<= 1) {
        int t = (threadIdx.x >= off) ? s[threadIdx.x - off] : 0;
        __syncthreads();
        s[threadIdx.x] += t;
        __syncthreads();
    }
    if (i < NN) rowp[i + 1] = s[threadIdx.x];
    if (threadIdx.x == 255) blks[blockIdx.x] = s[255];
}

// parallel exclusive scan of block totals (nb <= 128)
__global__ void scan2_kernel(int* __restrict__ blks, int nb) {
    __shared__ int s[128];
    int t = threadIdx.x;
    int v = (t < nb) ? blks[t] : 0;
    s[t] = v;
    __syncthreads();
    for (int off = 1; off < 128; off <<= 1) {
        int u = (t >= off) ? s[t - off] : 0;
        __syncthreads();
        s[t] += u;
        __syncthreads();
    }
    if (t < nb) blks[t] = s[t] - v;  // exclusive
}

__global__ void scan3_kernel(int* __restrict__ rowp, const int* __restrict__ blks) {
    int i = blockIdx.x * 256 + threadIdx.x;
    if (i < NN) rowp[i + 1] += blks[blockIdx.x];
    if (i == 0) rowp[0] = 0;
}

__global__ void copycur_kernel(const int* __restrict__ rowp, int* __restrict__ cur) {
    int i = blockIdx.x * 256 + threadIdx.x;
    if (i < NN) cur[i] = rowp[i];
}

__global__ void fill_kernel(const int* __restrict__ dst, int* __restrict__ cur, int* __restrict__ eid) {
    int i = blockIdx.x * blockDim.x + threadIdx.x;
    if (i < EE) {
        int pos = atomicAdd(&cur[dst[i]], 1);
        eid[pos] = i;
    }
}

// deterministic order: insertion-sort each node's edge list by edge id
__global__ void sortseg_kernel(const int* __restrict__ rowp, int* __restrict__ eid) {
    int n = blockIdx.x * 256 + threadIdx.x;
    if (n >= NN) return;
    int b = rowp[n], e = rowp[n + 1];
    for (int i = b + 1; i < e; ++i) {
        int key = eid[i];
        int j = i - 1;
        while (j >= b && eid[j] > key) { eid[j + 1] = eid[j]; --j; }
        eid[j + 1] = key;
    }
}

// gather src + edge-attr into CSR order (once per call, reused 4 layers)
__global__ void csr_gather_kernel(const int* __restrict__ csre, const int* __restrict__ srcA,
                                  const float* __restrict__ eattr,
                                  int* __restrict__ csrsrc, float4* __restrict__ ecsr) {
    int j = blockIdx.x * blockDim.x + threadIdx.x;
    if (j < EE) {
        int e = csre[j];
        csrsrc[j] = srcA[e];
        const float4* s = (const float4*)(eattr + (size_t)e * 8);
        ecsr[(size_t)j * 2] = s[0];
        ecsr[(size_t)j * 2 + 1] = s[1];
    }
}

// ---------------- per-layer: q,k,v,skip projections ----------------
// wave 0: q, wave 1: k, wave 2: v, wave 3: skip. lane owns channels 2l, 2l+1.
// k,v stored as fp16 pairs interleaved: uint2 slot {k0k1, v0v1} per (node,lane).
// block 0 also zeroes the per-layer stats region (bnpart/gmax/gsum).
__global__ __launch_bounds__(256) void qkvs_kernel(
    const float* __restrict__ hin,
    const float* __restrict__ Wq, const float* __restrict__ bq,
    const float* __restrict__ Wk, const float* __restrict__ bk,
    const float* __restrict__ Wv, const float* __restrict__ bv,
    const float* __restrict__ Ws, const float* __restrict__ bs,
    float2* __restrict__ qo, __half2* __restrict__ kvo,
    float2* __restrict__ so, float* __restrict__ lstats)
{
    if (blockIdx.x == 0) {
        for (int i = threadIdx.x; i < LSTATS_WORDS; i += 256) lstats[i] = 0.0f;
    }
    __shared__ float xs[32][32];
    int lane = threadIdx.x & 63;
    int sel = threadIdx.x >> 6;
    const float* W = (sel == 0) ? Wq : (sel == 1) ? Wk : (sel == 2) ? Wv : Ws;
    const float* bias = (sel == 0) ? bq : (sel == 1) ? bk : (sel == 2) ? bv : bs;
    float w0[32], w1[32];
#pragma unroll
    for (int f = 0; f < 32; ++f) {
        float2 t = *(const float2*)&W[f * 128 + 2 * lane];
        w0[f] = t.x; w1[f] = t.y;
    }
    float2 bvv = *(const float2*)&bias[2 * lane];

    for (int chunk = blockIdx.x * 32; chunk < NN; chunk += gridDim.x * 32) {
        __syncthreads();
        for (int i = threadIdx.x; i < 1024; i += 256) {
            int nn = chunk + (i >> 5);
            xs[i >> 5][i & 31] = (nn < NN) ? hin[nn * 32 + (i & 31)] : 0.0f;
        }
        __syncthreads();
        int nmax = NN - chunk; if (nmax > 32) nmax = 32;
        for (int nl = 0; nl < nmax; ++nl) {
            float a0 = bvv.x, a1 = bvv.y;
#pragma unroll
            for (int f = 0; f < 32; ++f) {
                float xv = xs[nl][f];
                a0 += xv * w0[f];
                a1 += xv * w1[f];
            }
            size_t node = (size_t)(chunk + nl);
            if (sel == 0)      qo[node * 64 + lane] = make_float2(a0, a1);
            else if (sel == 1) kvo[node * 128 + 2 * lane]     = __float22half2_rn(make_float2(a0, a1));
            else if (sel == 2) kvo[node * 128 + 2 * lane + 1] = __float22half2_rn(make_float2(a0, a1));
            else               so[node * 64 + lane] = make_float2(a0, a1);
        }
    }
}

// ---------------- fused attention + beta gate + Wlin + ELU + BN partials ----------------
// 4 waves/block, 1 dst node per wave. lane owns channels 2*lane, 2*lane+1 (same head).
__global__ __launch_bounds__(256) void attn_kernel(
    const float2* __restrict__ qb, const uint2* __restrict__ kvb,
    const float2* __restrict__ skb,
    const float4* __restrict__ eb4,       // ecsr (2 float4/slot)
    const int* __restrict__ srcArr,       // csrsrc[j]
    const int* __restrict__ rowp,
    const float* __restrict__ WeL, const float* __restrict__ beL,
    const float* __restrict__ WbL,
    const float* __restrict__ WlinL, const float* __restrict__ blinL,
    float* __restrict__ hlin, float* __restrict__ bnpart)
{
    __shared__ float shc[4 * 128];
    __shared__ float sbn[64];

    int tid = threadIdx.x;
    if (tid < 64) sbn[tid] = 0.0f;
    __syncthreads();

    int w = tid >> 6;
    int lane = tid & 63;
    int n = blockIdx.x * 4 + w;

    if (n < NN) {
        float w0[8], w1[8];
#pragma unroll
        for (int d = 0; d < 8; ++d) {
            float2 t = *(const float2*)&WeL[d * 128 + 2 * lane];
            w0[d] = t.x; w1[d] = t.y;
        }
        float2 be2 = *(const float2*)&beL[2 * lane];
        float2 wbo = *(const float2*)&WbL[2 * lane];
        float2 wbs = *(const float2*)&WbL[128 + 2 * lane];
        float2 wbd = *(const float2*)&WbL[256 + 2 * lane];

        float2 q2 = qb[(size_t)n * 64 + lane];
        float2 sk = skb[(size_t)n * 64 + lane];

        int beg = rowp[n], end = rowp[n + 1];
        int cnt = end - beg;

        float m = -1e30f, s = 0.0f, a0 = 0.0f, a1 = 0.0f;

        uint2 kvA = make_uint2(0u, 0u);
        float4 eaA0 = make_float4(0.f, 0.f, 0.f, 0.f), eaA1 = eaA0;
        int snB = 0;

        if (cnt > 0) {
            int snA = srcArr[beg];
            kvA  = kvb[(size_t)snA * 64 + lane];
            eaA0 = eb4[(size_t)beg * 2];
            eaA1 = eb4[(size_t)beg * 2 + 1];
            if (cnt > 1) snB = srcArr[beg + 1];
        }

        for (int j = beg; j < end; ++j) {
            uint2 kvN = kvA; float4 eaN0 = eaA0, eaN1 = eaA1;
            int snC = snB;
            if (j + 1 < end) {
                kvN  = kvb[(size_t)snB * 64 + lane];
                eaN0 = eb4[(size_t)(j + 1) * 2];
                eaN1 = eb4[(size_t)(j + 1) * 2 + 1];
            }
            if (j + 2 < end) snC = srcArr[j + 2];

            // compute with current edge (A)
            float e0 = be2.x, e1 = be2.y;
            e0 += eaA0.x * w0[0] + eaA0.y * w0[1] + eaA0.z * w0[2] + eaA0.w * w0[3]
                + eaA1.x * w0[4] + eaA1.y * w0[5] + eaA1.z * w0[6] + eaA1.w * w0[7];
            e1 += eaA0.x * w1[0] + eaA0.y * w1[1] + eaA0.z * w1[2] + eaA0.w * w1[3]
                + eaA1.x * w1[4] + eaA1.y * w1[5] + eaA1.z * w1[6] + eaA1.w * w1[7];
            float2 kf = __half22float2(*(const __half2*)&kvA.x);
            float2 vf = __half22float2(*(const __half2*)&kvA.y);
            float kj0 = kf.x + e0;
            float kj1 = kf.y + e1;
            float p = q2.x * kj0 + q2.y * kj1;
#pragma unroll
            for (int off = 1; off <= 8; off <<= 1) p += __shfl_xor(p, off);
            float al = p * RSQRT_C;
            float vv0 = vf.x + e0;
            float vv1 = vf.y + e1;
            float mn = fmaxf(m, al);
            float sc = __expf(m - mn);
            float wg = __expf(al - mn);
            s  = s * sc + wg;
            a0 = a0 * sc + wg * vv0;
            a1 = a1 * sc + wg * vv1;
            m = mn;
            kvA = kvN; eaA0 = eaN0; eaA1 = eaN1; snB = snC;
        }

        float out0 = (cnt > 0) ? (a0 / s) : 0.0f;
        float out1 = (cnt > 0) ? (a1 / s) : 0.0f;

        float t = out0 * wbo.x + sk.x * wbs.x + (out0 - sk.x) * wbd.x
                + out1 * wbo.y + sk.y * wbs.y + (out1 - sk.y) * wbd.y;
#pragma unroll
        for (int off = 1; off <= 32; off <<= 1) t += __shfl_xor(t, off);
        float beta = 1.0f / (1.0f + __expf(-t));
        float hc0 = beta * sk.x + (1.0f - beta) * out0;
        float hc1 = beta * sk.y + (1.0f - beta) * out1;
        shc[w * 128 + 2 * lane]     = hc0;
        shc[w * 128 + 2 * lane + 1] = hc1;
        // same-wave LDS RAW: no barrier needed
        int cc = lane & 31;
        int half = lane >> 5;
        float acc = 0.0f;
#pragma unroll 8
        for (int i = 0; i < 64; ++i) {
            int ch = half * 64 + i;
            acc += shc[w * 128 + ch] * WlinL[ch * 32 + cc];
        }
        acc += __shfl_xor(acc, 32);
        if (lane < 32) {
            float hv = acc + blinL[lane];
            hv = (hv > 0.0f) ? hv : expm1f(hv);
            hlin[n * 32 + lane] = hv;
            atomicAdd(&sbn[lane], hv);
            atomicAdd(&sbn[32 + lane], hv * hv);
        }
    }
    __syncthreads();
    if (tid < 64) atomicAdd(&bnpart[(blockIdx.x & (NREP - 1)) * 64 + tid], sbn[tid]);
}

// ---------------- normalize (BN finalize inline) + pooling atomics ----------------
__device__ __forceinline__ unsigned fmap_u(float x) {
    unsigned u = __float_as_uint(x);
    return (u & 0x80000000u) ? ~u : (u | 0x80000000u);
}
__device__ __forceinline__ float funmap_u(unsigned u) {
    unsigned b = (u & 0x80000000u) ? (u & 0x7fffffffu) : ~u;
    return __uint_as_float(b);
}

__global__ void norm_pool_kernel(const float* __restrict__ hl, const float* __restrict__ bnpart,
                                 const float* __restrict__ gamma, const float* __restrict__ bnbeta,
                                 const int* __restrict__ bidx, float* __restrict__ hc,
                                 unsigned* __restrict__ gmax, float* __restrict__ gsum,
                                 int doPool, int doWrite) {
    int i0 = blockIdx.x * blockDim.x + threadIdx.x;
    int stride = gridDim.x * blockDim.x;   // multiple of 32 -> c fixed per thread
    int c = i0 & 31;
    float sm = 0.0f, sq = 0.0f;
#pragma unroll
    for (int r = 0; r < NREP; ++r) { sm += bnpart[r * 64 + c]; sq += bnpart[r * 64 + 32 + c]; }
    float mean = sm * (1.0f / NN);
    float var = sq * (1.0f / NN) - mean * mean;
    float scale = gamma[c] * rsqrtf(var + 1e-5f);
    float shift = bnbeta[c] - mean * scale;
    const int tot = NN * 32;
    for (int i = i0; i < tot; i += stride) {
        int n = i >> 5;
        float val = hl[i] * scale + shift;
        if (doWrite) hc[i] = val;
        if (doPool) {
            int b = bidx[n];
            atomicMax(&gmax[b * 32 + c], fmap_u(val));
            atomicAdd(&gsum[b * 32 + c], val);
        }
    }
}

__global__ void pool_accum_kernel(const unsigned* __restrict__ gmax, const float* __restrict__ gsum,
                                  const float* __restrict__ counts, float* __restrict__ rep) {
    int i = blockIdx.x * blockDim.x + threadIdx.x;
    if (i < BB * 32) {
        int b = i >> 5, c = i & 31;
        rep[b * 64 + c] += funmap_u(gmax[i]);
        rep[b * 64 + 32 + c] += gsum[i] / counts[b];
    }
}

// ---------------- readout MLP: one block per graph ----------------
__device__ __forceinline__ float eluf(float x) { return x > 0.0f ? x : expm1f(x); }

__global__ __launch_bounds__(128) void readout_kernel(
    const float* __restrict__ rep,
    const float* __restrict__ W1, const float* __restrict__ b1,
    const float* __restrict__ W2, const float* __restrict__ b2,
    const float* __restrict__ W3, const float* __restrict__ b3,
    float* __restrict__ out)
{
    __shared__ float sr[64];
    __shared__ float sz1[128];
    __shared__ float sz2[64];
    int g = blockIdx.x;
    int t = threadIdx.x;
    if (t < 64) sr[t] = rep[g * 64 + t];
    __syncthreads();
    float acc = b1[t];
#pragma unroll 8
    for (int i = 0; i < 64; ++i) acc += sr[i] * W1[i * 128 + t];
    sz1[t] = eluf(acc);
    __syncthreads();
    if (t < 64) {
        float a2 = b2[t];
#pragma unroll 8
        for (int i = 0; i < 128; ++i) a2 += sz1[i] * W2[i * 64 + t];
        sz2[t] = eluf(a2);
    }
    __syncthreads();
    if (t < 64) {
        float p = sz2[t] * W3[t];
#pragma unroll
        for (int off = 1; off <= 32; off <<= 1) p += __shfl_xor(p, off);
        if (t == 0) out[g] = p + b3[0];
    }
}

// ---------------- host ----------------

extern "C" void kernel_launch(void* const* d_in, const int* in_sizes, int n_in,
                              void* d_out, int out_size, void* d_ws, size_t ws_size,
                              hipStream_t stream) {
    const float* x      = (const float*)d_in[0];
    const float* eattr  = (const float*)d_in[1];
    const int*   eidx   = (const int*)d_in[2];
    const int*   bidx   = (const int*)d_in[3];
    const float* Wq     = (const float*)d_in[4];
    const float* bq     = (const float*)d_in[5];
    const float* Wk     = (const float*)d_in[6];
    const float* bk     = (const float*)d_in[7];
    const float* Wv     = (const float*)d_in[8];
    const float* bv     = (const float*)d_in[9];
    const float* We     = (const float*)d_in[10];
    const float* be     = (const float*)d_in[11];
    const float* Wskip  = (const float*)d_in[12];
    const float* bskip  = (const float*)d_in[13];
    const float* Wbeta  = (const float*)d_in[14];
    const float* Wlin   = (const float*)d_in[15];
    const float* blin   = (const float*)d_in[16];
    const float* bng    = (const float*)d_in[17];
    const float* bnb    = (const float*)d_in[18];
    const float* W1     = (const float*)d_in[19];
    const float* b1     = (const float*)d_in[20];
    const float* W2     = (const float*)d_in[21];
    const float* b2     = (const float*)d_in[22];
    const float* W3     = (const float*)d_in[23];
    const float* b3     = (const float*)d_in[24];
    float* out = (float*)d_out;

    char* ws = (char*)d_ws;
    size_t off = 0;
    auto alloc = [&](size_t bytes) -> char* {
        char* p = ws + off;
        off = (off + bytes + 255) & ~(size_t)255;
        return p;
    };
    int*    rowp   = (int*)alloc((NN + 1) * 4);
    int*    deg    = (int*)alloc(NN * 4);
    int*    cur    = (int*)alloc(NN * 4);
    int*    csre   = (int*)alloc(EE * 4);
    int*    blks   = (int*)alloc(128 * 4);
    float*  counts = (float*)alloc(BB * 4 + BB * 64 * 4);   // counts + rep contiguous
    float*  rep    = counts + BB;
    float2* qB     = (float2*)alloc((size_t)NN * 64 * 8);
    __half2* kvB   = (__half2*)alloc((size_t)NN * 128 * 4);
    float2* skB    = (float2*)alloc((size_t)NN * 64 * 8);
    float*  hlin   = (float*)alloc((size_t)NN * 32 * 4);
    float*  hcur   = (float*)alloc((size_t)NN * 32 * 4);
    float*  lstats = (float*)alloc(LSTATS_WORDS * 4);       // bnpart + gmax + gsum
    float*    bnpart = lstats;
    unsigned* gmax   = (unsigned*)(lstats + NREP * 64);
    float*    gsum   = lstats + NREP * 64 + BB * 32;

    int*    csrsrc = (int*)alloc(EE * 4);
    float4* ecsr   = (float4*)alloc((size_t)EE * 32);

    const int* srcA = eidx;
    const int* dstA = eidx + EE;

    // --- graph prep (once per call) ---
    (void)hipMemsetAsync(deg, 0, NN * 4, stream);
    (void)hipMemsetAsync(rep, 0, BB * 64 * 4, stream);

    deg_kernel<<<(EE + 255) / 256, 256, 0, stream>>>(dstA, deg);
    counts_kernel<<<1, 64, 0, stream>>>(bidx, counts);
    scan1_kernel<<<98, 256, 0, stream>>>(deg, rowp, blks);
    scan2_kernel<<<1, 128, 0, stream>>>(blks, 98);
    scan3_kernel<<<98, 256, 0, stream>>>(rowp, blks);
    copycur_kernel<<<98, 256, 0, stream>>>(rowp, cur);
    fill_kernel<<<(EE + 255) / 256, 256, 0, stream>>>(dstA, cur, csre);
    sortseg_kernel<<<98, 256, 0, stream>>>(rowp, csre);
    csr_gather_kernel<<<(EE + 255) / 256, 256, 0, stream>>>(csre, srcA, eattr, csrsrc, ecsr);

    const float* hin = x;
    for (int l = 0; l < LL; ++l) {
        qkvs_kernel<<<782, 256, 0, stream>>>(
            hin,
            Wq + l * FF * HCC, bq + l * HCC,
            Wk + l * FF * HCC, bk + l * HCC,
            Wv + l * FF * HCC, bv + l * HCC,
            Wskip + l * FF * HCC, bskip + l * HCC,
            qB, kvB, skB, lstats);

        attn_kernel<<<(NN + 3) / 4, 256, 0, stream>>>(
            qB, (const uint2*)kvB, skB, ecsr, csrsrc, rowp,
            We + l * EDD * HCC, be + l * HCC,
            Wbeta + l * 3 * HCC,
            Wlin + l * HCC * FF, blin + l * FF,
            hlin, bnpart);

        norm_pool_kernel<<<800, 256, 0, stream>>>(hlin, bnpart, bng + l * FF, bnb + l * FF,
                                                  bidx, hcur, gmax, gsum,
                                                  (l > 0) ? 1 : 0, (l < LL - 1) ? 1 : 0);

        if (l > 0) {
            pool_accum_kernel<<<8, 256, 0, stream>>>(gmax, gsum, counts, rep);
        }
        hin = hcur;
    }

    readout_kernel<<<64, 128, 0, stream>>>(rep, W1, b1, W2, b2, W3, b3, out);
}

// Round 5
// 746.648 us; speedup vs baseline: 2.0766x; 1.0848x over previous
//
#include <hip/hip_runtime.h>
#include <hip/hip_bf16.h>
#include <hip/hip_fp16.h>
#include <math.h>

#define NN 25000
#define EE 400000
#define BB 64
#define FF 32
#define EDD 8
#define HH 4
#define CC 32
#define HCC 128
#define LL 4
#define LINN 128

#define RSQRT_C 0.17677669529663687f  // 1/sqrt(32)
#define NREP 16                        // bnpart replicas
#define LSTATS_WORDS (NREP * 64 + BB * 32 * 2)   // bnpart + gmax + gsum

// ---------------- CSR build ----------------

__global__ void deg_kernel(const int* __restrict__ dst, int* __restrict__ deg) {
    int i = blockIdx.x * blockDim.x + threadIdx.x;
    if (i < EE) atomicAdd(&deg[dst[i]], 1);
}

// batch_index is sorted: counts via binary search, zero atomics
__global__ void counts_kernel(const int* __restrict__ bidx, float* __restrict__ counts) {
    int b = threadIdx.x;
    if (b < BB) {
        int lo = 0, hi = NN;
        while (lo < hi) { int mid = (lo + hi) >> 1; if (bidx[mid] < b) lo = mid + 1; else hi = mid; }
        int s = lo;
        lo = 0; hi = NN;
        while (lo < hi) { int mid = (lo + hi) >> 1; if (bidx[mid] < b + 1) lo = mid + 1; else hi = mid; }
        counts[b] = (float)(lo - s);
    }
}

// inclusive scan within 256-blocks; writes to rowp[i+1], block totals to blks
__global__ void scan1_kernel(const int* __restrict__ deg, int* __restrict__ rowp, int* __restrict__ blks) {
    __shared__ int s[256];
    int i = blockIdx.x * 256 + threadIdx.x;
    int v = (i < NN) ? deg[i] : 0;
    s[threadIdx.x] = v;
    __syncthreads();
    for (int off = 1; off < 256; off <<= 1) {
        int t = (threadIdx.x >= off) ? s[threadIdx.x - off] : 0;
        __syncthreads();
        s[threadIdx.x] += t;
        __syncthreads();
    }
    if (i < NN) rowp[i + 1] = s[threadIdx.x];
    if (threadIdx.x == 255) blks[blockIdx.x] = s[255];
}

// parallel exclusive scan of block totals (nb <= 128)
__global__ void scan2_kernel(int* __restrict__ blks, int nb) {
    __shared__ int s[128];
    int t = threadIdx.x;
    int v = (t < nb) ? blks[t] : 0;
    s[t] = v;
    __syncthreads();
    for (int off = 1; off < 128; off <<= 1) {
        int u = (t >= off) ? s[t - off] : 0;
        __syncthreads();
        s[t] += u;
        __syncthreads();
    }
    if (t < nb) blks[t] = s[t] - v;  // exclusive
}

__global__ void scan3_kernel(int* __restrict__ rowp, const int* __restrict__ blks) {
    int i = blockIdx.x * 256 + threadIdx.x;
    if (i < NN) rowp[i + 1] += blks[blockIdx.x];
    if (i == 0) rowp[0] = 0;
}

__global__ void copycur_kernel(const int* __restrict__ rowp, int* __restrict__ cur) {
    int i = blockIdx.x * 256 + threadIdx.x;
    if (i < NN) cur[i] = rowp[i];
}

__global__ void fill_kernel(const int* __restrict__ dst, int* __restrict__ cur, int* __restrict__ eid) {
    int i = blockIdx.x * blockDim.x + threadIdx.x;
    if (i < EE) {
        int pos = atomicAdd(&cur[dst[i]], 1);
        eid[pos] = i;
    }
}

// deterministic order: insertion-sort each node's edge list by edge id
__global__ void sortseg_kernel(const int* __restrict__ rowp, int* __restrict__ eid) {
    int n = blockIdx.x * 256 + threadIdx.x;
    if (n >= NN) return;
    int b = rowp[n], e = rowp[n + 1];
    for (int i = b + 1; i < e; ++i) {
        int key = eid[i];
        int j = i - 1;
        while (j >= b && eid[j] > key) { eid[j + 1] = eid[j]; --j; }
        eid[j + 1] = key;
    }
}

// gather src + edge-attr into CSR order (once per call, reused 4 layers)
__global__ void csr_gather_kernel(const int* __restrict__ csre, const int* __restrict__ srcA,
                                  const float* __restrict__ eattr,
                                  int* __restrict__ csrsrc, float4* __restrict__ ecsr) {
    int j = blockIdx.x * blockDim.x + threadIdx.x;
    if (j < EE) {
        int e = csre[j];
        csrsrc[j] = srcA[e];
        const float4* s = (const float4*)(eattr + (size_t)e * 8);
        ecsr[(size_t)j * 2] = s[0];
        ecsr[(size_t)j * 2 + 1] = s[1];
    }
}

// ---------------- per-layer: q,k,v,skip projections ----------------
// wave 0: q, wave 1: k, wave 2: v, wave 3: skip. lane owns channels 2l, 2l+1.
// k,v stored as fp16 pairs interleaved: uint2 slot {k0k1, v0v1} per (node,lane).
// block 0 also zeroes the per-layer stats region (bnpart/gmax/gsum).
__global__ __launch_bounds__(256) void qkvs_kernel(
    const float* __restrict__ hin,
    const float* __restrict__ Wq, const float* __restrict__ bq,
    const float* __restrict__ Wk, const float* __restrict__ bk,
    const float* __restrict__ Wv, const float* __restrict__ bv,
    const float* __restrict__ Ws, const float* __restrict__ bs,
    float2* __restrict__ qo, __half2* __restrict__ kvo,
    float2* __restrict__ so, float* __restrict__ lstats)
{
    if (blockIdx.x == 0) {
        for (int i = threadIdx.x; i < LSTATS_WORDS; i += 256) lstats[i] = 0.0f;
    }
    __shared__ float xs[32][32];
    int lane = threadIdx.x & 63;
    int sel = threadIdx.x >> 6;
    const float* W = (sel == 0) ? Wq : (sel == 1) ? Wk : (sel == 2) ? Wv : Ws;
    const float* bias = (sel == 0) ? bq : (sel == 1) ? bk : (sel == 2) ? bv : bs;
    float w0[32], w1[32];
#pragma unroll
    for (int f = 0; f < 32; ++f) {
        float2 t = *(const float2*)&W[f * 128 + 2 * lane];
        w0[f] = t.x; w1[f] = t.y;
    }
    float2 bvv = *(const float2*)&bias[2 * lane];

    for (int chunk = blockIdx.x * 32; chunk < NN; chunk += gridDim.x * 32) {
        __syncthreads();
        for (int i = threadIdx.x; i < 1024; i += 256) {
            int nn = chunk + (i >> 5);
            xs[i >> 5][i & 31] = (nn < NN) ? hin[nn * 32 + (i & 31)] : 0.0f;
        }
        __syncthreads();
        int nmax = NN - chunk; if (nmax > 32) nmax = 32;
        for (int nl = 0; nl < nmax; ++nl) {
            float a0 = bvv.x, a1 = bvv.y;
#pragma unroll
            for (int f = 0; f < 32; ++f) {
                float xv = xs[nl][f];
                a0 += xv * w0[f];
                a1 += xv * w1[f];
            }
            size_t node = (size_t)(chunk + nl);
            if (sel == 0)      qo[node * 64 + lane] = make_float2(a0, a1);
            else if (sel == 1) kvo[node * 128 + 2 * lane]     = __float22half2_rn(make_float2(a0, a1));
            else if (sel == 2) kvo[node * 128 + 2 * lane + 1] = __float22half2_rn(make_float2(a0, a1));
            else               so[node * 64 + lane] = make_float2(a0, a1);
        }
    }
}

// ---------------- fused attention + beta gate + Wlin + ELU + BN partials ----------------
// 4 waves/block, 1 dst node per wave. lane owns channels 2*lane, 2*lane+1 (same head).
// Direct exp-sum softmax (no running max): only s,a0,a1 are loop-carried -> deep ILP.
__global__ __launch_bounds__(256) void attn_kernel(
    const float2* __restrict__ qb, const uint2* __restrict__ kvb,
    const float2* __restrict__ skb,
    const float4* __restrict__ eb4,       // ecsr (2 float4/slot)
    const int* __restrict__ srcArr,       // csrsrc[j]
    const int* __restrict__ rowp,
    const float* __restrict__ WeL, const float* __restrict__ beL,
    const float* __restrict__ WbL,
    const float* __restrict__ WlinL, const float* __restrict__ blinL,
    float* __restrict__ hlin, float* __restrict__ bnpart)
{
    __shared__ float shc[4 * 128];
    __shared__ float sbn[64];

    int tid = threadIdx.x;
    if (tid < 64) sbn[tid] = 0.0f;
    __syncthreads();

    int w = tid >> 6;
    int lane = tid & 63;
    int n = blockIdx.x * 4 + w;

    if (n < NN) {
        float w0[8], w1[8];
#pragma unroll
        for (int d = 0; d < 8; ++d) {
            float2 t = *(const float2*)&WeL[d * 128 + 2 * lane];
            w0[d] = t.x; w1[d] = t.y;
        }
        float2 be2 = *(const float2*)&beL[2 * lane];
        float2 wbo = *(const float2*)&WbL[2 * lane];
        float2 wbs = *(const float2*)&WbL[128 + 2 * lane];
        float2 wbd = *(const float2*)&WbL[256 + 2 * lane];

        float2 q2 = qb[(size_t)n * 64 + lane];
        q2.x *= RSQRT_C; q2.y *= RSQRT_C;          // fold 1/sqrt(C) into q
        float2 sk = skb[(size_t)n * 64 + lane];

        int beg = rowp[n], end = rowp[n + 1];
        int cnt = end - beg;

        float s = 0.0f, a0 = 0.0f, a1 = 0.0f;

        uint2 kvA = make_uint2(0u, 0u);
        float4 eaA0 = make_float4(0.f, 0.f, 0.f, 0.f), eaA1 = eaA0;
        int snB = 0;
        int last = end - 1;

        if (cnt > 0) {
            int snA = srcArr[beg];
            kvA  = kvb[(size_t)snA * 64 + lane];
            eaA0 = eb4[(size_t)beg * 2];
            eaA1 = eb4[(size_t)beg * 2 + 1];
            int j1 = (beg + 1 < end) ? beg + 1 : last;
            snB = srcArr[j1];
        }

        for (int j = beg; j < end; ++j) {
            // branchless prefetch of edge j+1 (clamped)
            int jn = (j + 1 < end) ? j + 1 : last;
            uint2 kvN  = kvb[(size_t)snB * 64 + lane];
            float4 eaN0 = eb4[(size_t)jn * 2];
            float4 eaN1 = eb4[(size_t)jn * 2 + 1];
            int j2 = (j + 2 < end) ? j + 2 : last;
            int snC = srcArr[j2];

            // compute with current edge (A)
            float e0 = be2.x, e1 = be2.y;
            e0 += eaA0.x * w0[0] + eaA0.y * w0[1] + eaA0.z * w0[2] + eaA0.w * w0[3]
                + eaA1.x * w0[4] + eaA1.y * w0[5] + eaA1.z * w0[6] + eaA1.w * w0[7];
            e1 += eaA0.x * w1[0] + eaA0.y * w1[1] + eaA0.z * w1[2] + eaA0.w * w1[3]
                + eaA1.x * w1[4] + eaA1.y * w1[5] + eaA1.z * w1[6] + eaA1.w * w1[7];
            float2 kf = __half22float2(*(const __half2*)&kvA.x);
            float2 vf = __half22float2(*(const __half2*)&kvA.y);
            float p = q2.x * (kf.x + e0) + q2.y * (kf.y + e1);
#pragma unroll
            for (int off = 1; off <= 8; off <<= 1) p += __shfl_xor(p, off);
            float wg = __expf(p);                 // |p| small by construction: no overflow
            s  += wg;
            a0 = fmaf(wg, vf.x + e0, a0);
            a1 = fmaf(wg, vf.y + e1, a1);

            kvA = kvN; eaA0 = eaN0; eaA1 = eaN1; snB = snC;
        }

        float rs = (cnt > 0) ? (1.0f / s) : 0.0f;
        float out0 = a0 * rs;
        float out1 = a1 * rs;

        float t = out0 * wbo.x + sk.x * wbs.x + (out0 - sk.x) * wbd.x
                + out1 * wbo.y + sk.y * wbs.y + (out1 - sk.y) * wbd.y;
#pragma unroll
        for (int off = 1; off <= 32; off <<= 1) t += __shfl_xor(t, off);
        float beta = 1.0f / (1.0f + __expf(-t));
        float hc0 = beta * sk.x + (1.0f - beta) * out0;
        float hc1 = beta * sk.y + (1.0f - beta) * out1;
        shc[w * 128 + 2 * lane]     = hc0;
        shc[w * 128 + 2 * lane + 1] = hc1;
        // same-wave LDS RAW: no barrier needed
        int cc = lane & 31;
        int half = lane >> 5;
        float acc = 0.0f;
#pragma unroll 8
        for (int i = 0; i < 64; ++i) {
            int ch = half * 64 + i;
            acc += shc[w * 128 + ch] * WlinL[ch * 32 + cc];
        }
        acc += __shfl_xor(acc, 32);
        if (lane < 32) {
            float hv = acc + blinL[lane];
            hv = (hv > 0.0f) ? hv : expm1f(hv);
            hlin[n * 32 + lane] = hv;
            atomicAdd(&sbn[lane], hv);
            atomicAdd(&sbn[32 + lane], hv * hv);
        }
    }
    __syncthreads();
    if (tid < 64) atomicAdd(&bnpart[(blockIdx.x & (NREP - 1)) * 64 + tid], sbn[tid]);
}

// ---------------- normalize (BN finalize inline) + pooling atomics ----------------
__device__ __forceinline__ unsigned fmap_u(float x) {
    unsigned u = __float_as_uint(x);
    return (u & 0x80000000u) ? ~u : (u | 0x80000000u);
}
__device__ __forceinline__ float funmap_u(unsigned u) {
    unsigned b = (u & 0x80000000u) ? (u & 0x7fffffffu) : ~u;
    return __uint_as_float(b);
}

__global__ void norm_pool_kernel(const float* __restrict__ hl, const float* __restrict__ bnpart,
                                 const float* __restrict__ gamma, const float* __restrict__ bnbeta,
                                 const int* __restrict__ bidx, float* __restrict__ hc,
                                 unsigned* __restrict__ gmax, float* __restrict__ gsum,
                                 int doPool, int doWrite) {
    int i0 = blockIdx.x * blockDim.x + threadIdx.x;
    int stride = gridDim.x * blockDim.x;   // multiple of 32 -> c fixed per thread
    int c = i0 & 31;
    float sm = 0.0f, sq = 0.0f;
#pragma unroll
    for (int r = 0; r < NREP; ++r) { sm += bnpart[r * 64 + c]; sq += bnpart[r * 64 + 32 + c]; }
    float mean = sm * (1.0f / NN);
    float var = sq * (1.0f / NN) - mean * mean;
    float scale = gamma[c] * rsqrtf(var + 1e-5f);
    float shift = bnbeta[c] - mean * scale;
    const int tot = NN * 32;
    for (int i = i0; i < tot; i += stride) {
        int n = i >> 5;
        float val = hl[i] * scale + shift;
        if (doWrite) hc[i] = val;
        if (doPool) {
            int b = bidx[n];
            atomicMax(&gmax[b * 32 + c], fmap_u(val));
            atomicAdd(&gsum[b * 32 + c], val);
        }
    }
}

__global__ void pool_accum_kernel(const unsigned* __restrict__ gmax, const float* __restrict__ gsum,
                                  const float* __restrict__ counts, float* __restrict__ rep) {
    int i = blockIdx.x * blockDim.x + threadIdx.x;
    if (i < BB * 32) {
        int b = i >> 5, c = i & 31;
        rep[b * 64 + c] += funmap_u(gmax[i]);
        rep[b * 64 + 32 + c] += gsum[i] / counts[b];
    }
}

// ---------------- readout MLP: one block per graph ----------------
__device__ __forceinline__ float eluf(float x) { return x > 0.0f ? x : expm1f(x); }

__global__ __launch_bounds__(128) void readout_kernel(
    const float* __restrict__ rep,
    const float* __restrict__ W1, const float* __restrict__ b1,
    const float* __restrict__ W2, const float* __restrict__ b2,
    const float* __restrict__ W3, const float* __restrict__ b3,
    float* __restrict__ out)
{
    __shared__ float sr[64];
    __shared__ float sz1[128];
    __shared__ float sz2[64];
    int g = blockIdx.x;
    int t = threadIdx.x;
    if (t < 64) sr[t] = rep[g * 64 + t];
    __syncthreads();
    float acc = b1[t];
#pragma unroll 8
    for (int i = 0; i < 64; ++i) acc += sr[i] * W1[i * 128 + t];
    sz1[t] = eluf(acc);
    __syncthreads();
    if (t < 64) {
        float a2 = b2[t];
#pragma unroll 8
        for (int i = 0; i < 128; ++i) a2 += sz1[i] * W2[i * 64 + t];
        sz2[t] = eluf(a2);
    }
    __syncthreads();
    if (t < 64) {
        float p = sz2[t] * W3[t];
#pragma unroll
        for (int off = 1; off <= 32; off <<= 1) p += __shfl_xor(p, off);
        if (t == 0) out[g] = p + b3[0];
    }
}

// ---------------- host ----------------

extern "C" void kernel_launch(void* const* d_in, const int* in_sizes, int n_in,
                              void* d_out, int out_size, void* d_ws, size_t ws_size,
                              hipStream_t stream) {
    const float* x      = (const float*)d_in[0];
    const float* eattr  = (const float*)d_in[1];
    const int*   eidx   = (const int*)d_in[2];
    const int*   bidx   = (const int*)d_in[3];
    const float* Wq     = (const float*)d_in[4];
    const float* bq     = (const float*)d_in[5];
    const float* Wk     = (const float*)d_in[6];
    const float* bk     = (const float*)d_in[7];
    const float* Wv     = (const float*)d_in[8];
    const float* bv     = (const float*)d_in[9];
    const float* We     = (const float*)d_in[10];
    const float* be     = (const float*)d_in[11];
    const float* Wskip  = (const float*)d_in[12];
    const float* bskip  = (const float*)d_in[13];
    const float* Wbeta  = (const float*)d_in[14];
    const float* Wlin   = (const float*)d_in[15];
    const float* blin   = (const float*)d_in[16];
    const float* bng    = (const float*)d_in[17];
    const float* bnb    = (const float*)d_in[18];
    const float* W1     = (const float*)d_in[19];
    const float* b1     = (const float*)d_in[20];
    const float* W2     = (const float*)d_in[21];
    const float* b2     = (const float*)d_in[22];
    const float* W3     = (const float*)d_in[23];
    const float* b3     = (const float*)d_in[24];
    float* out = (float*)d_out;

    char* ws = (char*)d_ws;
    size_t off = 0;
    auto alloc = [&](size_t bytes) -> char* {
        char* p = ws + off;
        off = (off + bytes + 255) & ~(size_t)255;
        return p;
    };
    int*    rowp   = (int*)alloc((NN + 1) * 4);
    int*    deg    = (int*)alloc(NN * 4);
    int*    cur    = (int*)alloc(NN * 4);
    int*    csre   = (int*)alloc(EE * 4);
    int*    blks   = (int*)alloc(128 * 4);
    float*  counts = (float*)alloc(BB * 4 + BB * 64 * 4);   // counts + rep contiguous
    float*  rep    = counts + BB;
    float2* qB     = (float2*)alloc((size_t)NN * 64 * 8);
    __half2* kvB   = (__half2*)alloc((size_t)NN * 128 * 4);
    float2* skB    = (float2*)alloc((size_t)NN * 64 * 8);
    float*  hlin   = (float*)alloc((size_t)NN * 32 * 4);
    float*  hcur   = (float*)alloc((size_t)NN * 32 * 4);
    float*  lstats = (float*)alloc(LSTATS_WORDS * 4);       // bnpart + gmax + gsum
    float*    bnpart = lstats;
    unsigned* gmax   = (unsigned*)(lstats + NREP * 64);
    float*    gsum   = lstats + NREP * 64 + BB * 32;

    int*    csrsrc = (int*)alloc(EE * 4);
    float4* ecsr   = (float4*)alloc((size_t)EE * 32);

    const int* srcA = eidx;
    const int* dstA = eidx + EE;

    // --- graph prep (once per call) ---
    (void)hipMemsetAsync(deg, 0, NN * 4, stream);
    (void)hipMemsetAsync(rep, 0, BB * 64 * 4, stream);

    deg_kernel<<<(EE + 255) / 256, 256, 0, stream>>>(dstA, deg);
    counts_kernel<<<1, 64, 0, stream>>>(bidx, counts);
    scan1_kernel<<<98, 256, 0, stream>>>(deg, rowp, blks);
    scan2_kernel<<<1, 128, 0, stream>>>(blks, 98);
    scan3_kernel<<<98, 256, 0, stream>>>(rowp, blks);
    copycur_kernel<<<98, 256, 0, stream>>>(rowp, cur);
    fill_kernel<<<(EE + 255) / 256, 256, 0, stream>>>(dstA, cur, csre);
    sortseg_kernel<<<98, 256, 0, stream>>>(rowp, csre);
    csr_gather_kernel<<<(EE + 255) / 256, 256, 0, stream>>>(csre, srcA, eattr, csrsrc, ecsr);

    const float* hin = x;
    for (int l = 0; l < LL; ++l) {
        qkvs_kernel<<<782, 256, 0, stream>>>(
            hin,
            Wq + l * FF * HCC, bq + l * HCC,
            Wk + l * FF * HCC, bk + l * HCC,
            Wv + l * FF * HCC, bv + l * HCC,
            Wskip + l * FF * HCC, bskip + l * HCC,
            qB, kvB, skB, lstats);

        attn_kernel<<<(NN + 3) / 4, 256, 0, stream>>>(
            qB, (const uint2*)kvB, skB, ecsr, csrsrc, rowp,
            We + l * EDD * HCC, be + l * HCC,
            Wbeta + l * 3 * HCC,
            Wlin + l * HCC * FF, blin + l * FF,
            hlin, bnpart);

        norm_pool_kernel<<<800, 256, 0, stream>>>(hlin, bnpart, bng + l * FF, bnb + l * FF,
                                                  bidx, hcur, gmax, gsum,
                                                  (l > 0) ? 1 : 0, (l < LL - 1) ? 1 : 0);

        if (l > 0) {
            pool_accum_kernel<<<8, 256, 0, stream>>>(gmax, gsum, counts, rep);
        }
        hin = hcur;
    }

    readout_kernel<<<64, 128, 0, stream>>>(rep, W1, b1, W2, b2, W3, b3, out);
}